// Round 11
// baseline (252.888 us; speedup 1.0000x reference)
//
#include <hip/hip_runtime.h>

static constexpr int kD = 128;
static constexpr int kHedges = 20000;

// Coarse partition: edge by h>>7 (128 hedges/bucket), node by n>>8 (256 nodes/bucket)
static constexpr int kNCE = 157;      // ceil(20000/128)
static constexpr int kCapCE = 11264;  // mean 10240 + 10 sigma
static constexpr int kNCN = 391;      // ceil(100000/256)
static constexpr int kCapCN = 4608;   // mean 4096 + ~8 sigma
// gather slice caps
static constexpr int kSliceE4 = 1664; // 16 hedges/block: mean 1280 + ~10.6 sigma
static constexpr int kSliceN4 = 1408; // 64 nodes/block: mean 1024 + ~12 sigma
// partition block-local staging capacity (per_block = ceil(n_pairs/pgrid) must be <= this)
static constexpr int kPmax = 3200;    // 512 chunks: long runs -> coalesced writeback wins
static constexpr int kNBmax = 391;    // max(kNCE, kNCN)

typedef __attribute__((ext_vector_type(8))) short bf16x8;
typedef __attribute__((ext_vector_type(4))) float f32x4;

__device__ __forceinline__ float u2f(unsigned u) { return __uint_as_float(u); }
__device__ __forceinline__ unsigned f2u(float f) { return __float_as_uint(f); }

// round-to-nearest-even fp32 -> bf16, pack two into one uint
__device__ __forceinline__ unsigned bfpack(float x, float y) {
  unsigned ux = f2u(x); ux = (ux + 0x7FFFu + ((ux >> 16) & 1u)) >> 16;
  unsigned uy = f2u(y); uy = (uy + 0x7FFFu + ((uy >> 16) & 1u)) & 0xFFFF0000u;
  return ux | uy;
}
// accumulate 8 bf16 (uint4) into a[0..7]
__device__ __forceinline__ void bf8_acc(uint4 v, float* a) {
  a[0] += u2f(v.x << 16); a[1] += u2f(v.x & 0xFFFF0000u);
  a[2] += u2f(v.y << 16); a[3] += u2f(v.y & 0xFFFF0000u);
  a[4] += u2f(v.z << 16); a[5] += u2f(v.z & 0xFFFF0000u);
  a[6] += u2f(v.w << 16); a[7] += u2f(v.w & 0xFFFF0000u);
}

// ---------- L1: convert feats + W (fused) + partition pairs into coarse buckets ----
// Split by key side: blocks [0,pgrid) edge keying, [pgrid,2*pgrid) node keying.
// Block-local counting-sort in LDS, coalesced per-bucket run writeback.
__global__ __launch_bounds__(512) void partition_coarse(
    const float* __restrict__ feat, unsigned* __restrict__ feat_bf, int n_feat,
    const float* __restrict__ W, unsigned* __restrict__ Wbf,
    const int* __restrict__ node_idx, const int* __restrict__ hedge_idx,
    int n_pairs, int pgrid,
    int* __restrict__ gcnt_e, int* __restrict__ buf_e,
    int* __restrict__ gcnt_n, int* __restrict__ buf_n) {
  __shared__ unsigned lbuf[kPmax];            // 12.8 KB
  __shared__ int hist[kNBmax], gshift[kNBmax];
  __shared__ int wtot[8];
  const int tid = threadIdx.x;
  // fused feature conversion (grid-stride over uint4 groups of 8 floats)
  {
    const int n8 = n_feat >> 3;
    for (int t = blockIdx.x * 512 + tid; t < n8; t += gridDim.x * 512) {
      long long i = (long long)t * 8;
      const float4 v0 = *(const float4*)(feat + i);
      const float4 v1 = *(const float4*)(feat + i + 4);
      uint4 o;
      o.x = bfpack(v0.x, v0.y); o.y = bfpack(v0.z, v0.w);
      o.z = bfpack(v1.x, v1.y); o.w = bfpack(v1.z, v1.w);
      *(uint4*)(feat_bf + (i >> 1)) = o;
    }
  }
  // fused W bf16 packing, ROW-major for MFMA B-frags:
  // Wbf[row*64 + m] = {W[row][2m], W[row][2m+1]}  (32 KB total)
  for (int t = blockIdx.x * 512 + tid; t < kD * 64; t += gridDim.x * 512) {
    int row = t >> 6, m = t & 63;
    Wbf[t] = bfpack(W[row * kD + 2 * m], W[row * kD + 2 * m + 1]);
  }
  // side selection (uniform per block -> no divergence)
  const bool isEdge = (blockIdx.x < pgrid);
  const int cchunk = isEdge ? blockIdx.x : blockIdx.x - pgrid;
  const int per_block = (n_pairs + pgrid - 1) / pgrid;
  const int s = cchunk * per_block;
  const int e = min(s + per_block, n_pairs);
  const int cnt = max(e - s, 0);              // <= kPmax by grid sizing
  const int nb      = isEdge ? kNCE : kNCN;
  const int shift   = isEdge ? 7 : 8;         // key -> coarse bucket
  const int pshift  = isEdge ? 15 : 17;       // payload pack shift (h<2^15, n<2^17)
  const int* __restrict__ kidx = isEdge ? hedge_idx : node_idx;
  const int* __restrict__ pidx = isEdge ? node_idx : hedge_idx;
  int* __restrict__ gcnt = isEdge ? gcnt_e : gcnt_n;
  int* __restrict__ bufo = isEdge ? buf_e : buf_n;
  const long long capc = isEdge ? kCapCE : kCapCN;
  const unsigned kmask = (1u << pshift) - 1u;
  const int lowmask = (1 << shift) - 1;

  for (int i = tid; i < nb; i += 512) hist[i] = 0;
  __syncthreads();
  // pass 1: local histogram of this block's chunk under this side's keying
  for (int i = s + tid; i < e; i += 512) atomicAdd(&hist[kidx[i] >> shift], 1);
  __syncthreads();
  // exclusive scan of hist[0..nb) (nb <= 391 <= 512 threads, wave-hierarchical)
  {
    const int lane = tid & 63, wid = tid >> 6;
    int v = (tid < nb) ? hist[tid] : 0;
    int x = v;
#pragma unroll
    for (int d = 1; d < 64; d <<= 1) {
      int y = __shfl_up(x, d, 64);
      if (lane >= d) x += y;
    }
    if (lane == 63) wtot[wid] = x;
    __syncthreads();
    int add = 0;
    for (int w = 0; w < wid; ++w) add += wtot[w];
    if (tid < nb) {
      int lofs = x + add - v;
      int base = (v > 0) ? atomicAdd(&gcnt[tid], v) : 0;
      gshift[tid] = base - lofs;   // global pos = gshift[b] + lds_slot
      hist[tid] = lofs;            // reuse as placement cursor
    }
  }
  __syncthreads();
  // pass 2: block-local counting-sort placement into LDS (packed key+payload)
  for (int i = s + tid; i < e; i += 512) {
    const unsigned k = (unsigned)kidx[i];
    const unsigned p = (unsigned)pidx[i];
    const int b = (int)(k >> shift);
    const int pos = atomicAdd(&hist[b], 1);
    lbuf[pos] = (p << pshift) | k;
  }
  __syncthreads();
  // writeback: consecutive LDS slots within a bucket run -> consecutive global
  // addresses (coalesced, full lines, one XCD per run)
  for (int i = tid; i < cnt; i += 512) {
    const unsigned v = lbuf[i];
    const int k = (int)(v & kmask);
    const int p = (int)(v >> pshift);
    const int b = k >> shift;
    const int pe = gshift[b] + i;
    if (pe < capc) bufo[(long long)b * capc + pe] = (p << shift) | (k & lowmask);
  }
}

// ---------- L2a: sort EDGE coarse buckets by low 7 key bits, in place; emit segs --
__global__ __launch_bounds__(1024) void subsort_edge(
    int* __restrict__ buf_e, const int* __restrict__ gcnt_e, int* __restrict__ seg_e) {
  __shared__ int sbuf[kCapCE];       // 45 KB
  __shared__ int bins[129];
  __shared__ int cur[128];
  __shared__ int segs[129];
  __shared__ int wtot[16];
  const int tid = threadIdx.x;
  const int cb = blockIdx.x;
  int* src = buf_e + (long long)cb * kCapCE;
  const int cnt = min(gcnt_e[cb], kCapCE);
  int* segout = seg_e + cb * 129;
  if (tid < 128) bins[tid] = 0;
  __syncthreads();
  for (int i = tid; i < cnt; i += 1024) atomicAdd(&bins[src[i] & 127], 1);
  __syncthreads();
  const int lane = tid & 63, wid = tid >> 6;
  int v = (tid < 128) ? bins[tid] : 0;
  int x = v;
#pragma unroll
  for (int d = 1; d < 64; d <<= 1) {
    int y = __shfl_up(x, d, 64);
    if (lane >= d) x += y;
  }
  if (lane == 63) wtot[wid] = x;
  __syncthreads();
  int add = 0;
  for (int w = 0; w < wid; ++w) add += wtot[w];
  if (tid < 128) { segs[tid + 1] = x + add; cur[tid] = x + add - v; }
  if (tid == 0) segs[0] = 0;
  __syncthreads();
  for (int i = tid; i < cnt; i += 1024) {
    int p = src[i];
    int r = atomicAdd(&cur[p & 127], 1);
    sbuf[r] = p >> 7;                // payload only: sorted adjacency
  }
  __syncthreads();
  for (int i = tid; i < cnt; i += 1024) src[i] = sbuf[i];   // coalesced writeback
  if (tid <= 128) segout[tid] = segs[tid];
}

// ---------- L2b+L3 fused: node-subsort blocks ride under the fabric-bound gather --
// blocks [0,kNCN): sort one node coarse bucket (256 bins, cap 4608; 21.5 KB LDS).
// blocks [kNCN, ...): gather features -> mean -> @W.T via MFMA -> t_edge bf16.
// The gather is at its random-fetch fabric roofline (172 MB compulsory @ ~3.1 TB/s,
// VALU 75% idle) so the sort blocks ride in its shadow; LDS union 21.5 KB keeps
// the gather's block/CU ceiling at 7 (>= its measured ~4).
struct ShmGather {
  float hout[16][132];               // 8448 B (16-aligned first)
  unsigned hbf[16][68];              // 4352 B (16B-aligned: 8448%16==0)
  int ebuf[kSliceE4];                // 6656 B
  int segl[17];
};
struct ShmSort {
  int sbuf[kCapCN];                  // 18432 B
  int bins[257];
  int cur[256];
  int segs[257];
  int wtot[4];
};
union __align__(16) ShmU { ShmGather g; ShmSort s; };

__global__ __launch_bounds__(256) void gather_edge_sortn(
    const unsigned* __restrict__ feat_bf, const int* __restrict__ buf_e,
    const int* __restrict__ seg_e, const unsigned* __restrict__ Wbf,
    unsigned* __restrict__ t_edge, int n_hedges,
    int* __restrict__ buf_n, const int* __restrict__ gcnt_n,
    int* __restrict__ seg_n) {
  __shared__ ShmU sh;
  const int tid = threadIdx.x;
  if (blockIdx.x < kNCN) {
    // ---- node subsort role (256 threads) ----
    const int cb = blockIdx.x;
    int* src = buf_n + (long long)cb * kCapCN;
    const int cnt = min(gcnt_n[cb], kCapCN);
    int* segout = seg_n + cb * 257;
    sh.s.bins[tid] = 0;
    __syncthreads();
    for (int i = tid; i < cnt; i += 256) atomicAdd(&sh.s.bins[src[i] & 255], 1);
    __syncthreads();
    const int lane = tid & 63, wid = tid >> 6;
    int v = sh.s.bins[tid];
    int x = v;
#pragma unroll
    for (int d = 1; d < 64; d <<= 1) {
      int y = __shfl_up(x, d, 64);
      if (lane >= d) x += y;
    }
    if (lane == 63) sh.s.wtot[wid] = x;
    __syncthreads();
    int add = 0;
    for (int w = 0; w < wid; ++w) add += sh.s.wtot[w];
    sh.s.segs[tid + 1] = x + add;
    sh.s.cur[tid] = x + add - v;
    if (tid == 0) sh.s.segs[0] = 0;
    __syncthreads();
    for (int i = tid; i < cnt; i += 256) {
      int p = src[i];
      int r = atomicAdd(&sh.s.cur[p & 255], 1);
      sh.s.sbuf[r] = p >> 8;           // payload only: sorted adjacency
    }
    __syncthreads();
    for (int i = tid; i < cnt; i += 256) src[i] = sh.s.sbuf[i];
    for (int j = tid; j <= 256; j += 256) segout[j] = sh.s.segs[j];
    return;
  }
  // ---- gather role: 16 hedges per block ----
  const int b = blockIdx.x - kNCN;
  const int h0 = b * 16;
  const int cb = h0 >> 7, j0 = h0 & 127;
  if (tid < 17) sh.g.segl[tid] = seg_e[cb * 129 + j0 + tid];
  __syncthreads();
  const int sbase = sh.g.segl[0];
  const int n_sl = min(sh.g.segl[16] - sbase, kSliceE4);
  const int* src = buf_e + (long long)cb * kCapCE + sbase;
  for (int i = tid; i < n_sl; i += 256) sh.g.ebuf[i] = src[i];
  __syncthreads();
  const int g = tid >> 4, lane = tid & 15, cw = lane * 4;
  const int gh = h0 + g;
  float a[8] = {}, a2[8] = {};
  int deg = 0;
  if (gh < n_hedges) {
    deg = sh.g.segl[g + 1] - sh.g.segl[g];
    const int s0 = min(sh.g.segl[g] - sbase, n_sl);
    const int e0 = min(sh.g.segl[g + 1] - sbase, n_sl);
    int j = s0;
    const int jend8 = s0 + ((e0 - s0) & ~7);
    if (j < jend8) {
      uint4 A0 = *(const uint4*)(feat_bf + (long long)sh.g.ebuf[j] * 64 + cw);
      uint4 A1 = *(const uint4*)(feat_bf + (long long)sh.g.ebuf[j + 1] * 64 + cw);
      uint4 A2 = *(const uint4*)(feat_bf + (long long)sh.g.ebuf[j + 2] * 64 + cw);
      uint4 A3 = *(const uint4*)(feat_bf + (long long)sh.g.ebuf[j + 3] * 64 + cw);
      uint4 A4 = *(const uint4*)(feat_bf + (long long)sh.g.ebuf[j + 4] * 64 + cw);
      uint4 A5 = *(const uint4*)(feat_bf + (long long)sh.g.ebuf[j + 5] * 64 + cw);
      uint4 A6 = *(const uint4*)(feat_bf + (long long)sh.g.ebuf[j + 6] * 64 + cw);
      uint4 A7 = *(const uint4*)(feat_bf + (long long)sh.g.ebuf[j + 7] * 64 + cw);
      j += 8;
      for (; j < jend8; j += 8) {
        uint4 B0 = *(const uint4*)(feat_bf + (long long)sh.g.ebuf[j] * 64 + cw);
        uint4 B1 = *(const uint4*)(feat_bf + (long long)sh.g.ebuf[j + 1] * 64 + cw);
        uint4 B2 = *(const uint4*)(feat_bf + (long long)sh.g.ebuf[j + 2] * 64 + cw);
        uint4 B3 = *(const uint4*)(feat_bf + (long long)sh.g.ebuf[j + 3] * 64 + cw);
        uint4 B4 = *(const uint4*)(feat_bf + (long long)sh.g.ebuf[j + 4] * 64 + cw);
        uint4 B5 = *(const uint4*)(feat_bf + (long long)sh.g.ebuf[j + 5] * 64 + cw);
        uint4 B6 = *(const uint4*)(feat_bf + (long long)sh.g.ebuf[j + 6] * 64 + cw);
        uint4 B7 = *(const uint4*)(feat_bf + (long long)sh.g.ebuf[j + 7] * 64 + cw);
        bf8_acc(A0, a); bf8_acc(A1, a2); bf8_acc(A2, a); bf8_acc(A3, a2);
        bf8_acc(A4, a); bf8_acc(A5, a2); bf8_acc(A6, a); bf8_acc(A7, a2);
        A0 = B0; A1 = B1; A2 = B2; A3 = B3;
        A4 = B4; A5 = B5; A6 = B6; A7 = B7;
      }
      bf8_acc(A0, a); bf8_acc(A1, a2); bf8_acc(A2, a); bf8_acc(A3, a2);
      bf8_acc(A4, a); bf8_acc(A5, a2); bf8_acc(A6, a); bf8_acc(A7, a2);
    }
    for (; j < e0; ++j) {
      uint4 v = *(const uint4*)(feat_bf + (long long)sh.g.ebuf[j] * 64 + cw);
      bf8_acc(v, a);
    }
  }
  {
    const float inv = 1.0f / fmaxf((float)deg, 1.0f);
    uint4 o;
    o.x = bfpack((a[0] + a2[0]) * inv, (a[1] + a2[1]) * inv);
    o.y = bfpack((a[2] + a2[2]) * inv, (a[3] + a2[3]) * inv);
    o.z = bfpack((a[4] + a2[4]) * inv, (a[5] + a2[5]) * inv);
    o.w = bfpack((a[6] + a2[6]) * inv, (a[7] + a2[7]) * inv);
    *(uint4*)(&sh.g.hbf[g][cw]) = o;   // row stride 68 words = 272 B (16B-aligned)
  }
  __syncthreads();
  // MFMA GEMM: wave wv handles col-tiles 2wv, 2wv+1.
  {
    const int wv = tid >> 6;
    const int l = tid & 63;
    const int frow = l & 15;
    const int kgrp = l >> 4;
    f32x4 acc0 = {0.f, 0.f, 0.f, 0.f}, acc1 = {0.f, 0.f, 0.f, 0.f};
#pragma unroll
    for (int kk = 0; kk < 4; ++kk) {
      const int wofs = kk * 16 + kgrp * 4;
      bf16x8 af = *(const bf16x8*)(&sh.g.hbf[frow][wofs]);
      bf16x8 bf0 = *(const bf16x8*)(Wbf + ((2 * wv) * 16 + frow) * 64 + wofs);
      bf16x8 bf1 = *(const bf16x8*)(Wbf + ((2 * wv + 1) * 16 + frow) * 64 + wofs);
      acc0 = __builtin_amdgcn_mfma_f32_16x16x32_bf16(af, bf0, acc0, 0, 0, 0);
      acc1 = __builtin_amdgcn_mfma_f32_16x16x32_bf16(af, bf1, acc1, 0, 0, 0);
    }
    // C/D layout: col = l&15, row = (l>>4)*4 + r  [m89-verified]
#pragma unroll
    for (int r = 0; r < 4; ++r) {
      sh.g.hout[kgrp * 4 + r][(2 * wv) * 16 + frow] = acc0[r];
      sh.g.hout[kgrp * 4 + r][(2 * wv + 1) * 16 + frow] = acc1[r];
    }
  }
  __syncthreads();
  if (gh < n_hedges) {
    const float* hr = &sh.g.hout[g][lane * 8];
    uint4 o;
    o.x = bfpack(hr[0], hr[1]);
    o.y = bfpack(hr[2], hr[3]);
    o.z = bfpack(hr[4], hr[5]);
    o.w = bfpack(hr[6], hr[7]);
    *(uint4*)(t_edge + (long long)gh * 64 + cw) = o;
  }
}

// ---------- gather t_edge -> fp32 out (mean) + bias, MLP-pipelined ----------
// 256 thr / 64 nodes per block (16 groups x 16 lanes, 4 nodes per group).
__global__ __launch_bounds__(256) void gather_node_v4(
    const unsigned* __restrict__ t_edge, const int* __restrict__ buf_n,
    const int* __restrict__ seg_n, const float* __restrict__ bias,
    float* __restrict__ out, int n_nodes) {
  __shared__ int ebuf[kSliceN4];
  __shared__ int segl[65];
  const int b = blockIdx.x;            // 64 nodes per block; 256%64==0 -> one bucket
  const int tid = threadIdx.x;
  const int n0 = b * 64;
  const int cb = n0 >> 8, j0 = n0 & 255;
  if (tid < 65) segl[tid] = seg_n[cb * 257 + j0 + tid];
  __syncthreads();
  const int sbase = segl[0];
  const int n_sl = min(segl[64] - sbase, kSliceN4);
  const int* src = buf_n + (long long)cb * kCapCN + sbase;
  for (int i = tid; i < n_sl; i += 256) ebuf[i] = src[i];
  __syncthreads();
  const int g = tid >> 4, lane = tid & 15, cw = lane * 4;
  const float4 b0 = *(const float4*)(bias + lane * 8);
  const float4 b1 = *(const float4*)(bias + lane * 8 + 4);
  for (int nl = g; nl < 64; nl += 16) {
    int gn = n0 + nl;
    if (gn >= n_nodes) continue;
    const int deg = segl[nl + 1] - segl[nl];
    const int s0 = min(segl[nl] - sbase, n_sl);
    const int e0 = min(segl[nl + 1] - sbase, n_sl);
    float a[8] = {}, a2[8] = {};
    int j = s0;
    const int jend8 = s0 + ((e0 - s0) & ~7);
    if (j < jend8) {
      uint4 A0 = *(const uint4*)(t_edge + (long long)ebuf[j] * 64 + cw);
      uint4 A1 = *(const uint4*)(t_edge + (long long)ebuf[j + 1] * 64 + cw);
      uint4 A2 = *(const uint4*)(t_edge + (long long)ebuf[j + 2] * 64 + cw);
      uint4 A3 = *(const uint4*)(t_edge + (long long)ebuf[j + 3] * 64 + cw);
      uint4 A4 = *(const uint4*)(t_edge + (long long)ebuf[j + 4] * 64 + cw);
      uint4 A5 = *(const uint4*)(t_edge + (long long)ebuf[j + 5] * 64 + cw);
      uint4 A6 = *(const uint4*)(t_edge + (long long)ebuf[j + 6] * 64 + cw);
      uint4 A7 = *(const uint4*)(t_edge + (long long)ebuf[j + 7] * 64 + cw);
      j += 8;
      for (; j < jend8; j += 8) {
        uint4 B0 = *(const uint4*)(t_edge + (long long)ebuf[j] * 64 + cw);
        uint4 B1 = *(const uint4*)(t_edge + (long long)ebuf[j + 1] * 64 + cw);
        uint4 B2 = *(const uint4*)(t_edge + (long long)ebuf[j + 2] * 64 + cw);
        uint4 B3 = *(const uint4*)(t_edge + (long long)ebuf[j + 3] * 64 + cw);
        uint4 B4 = *(const uint4*)(t_edge + (long long)ebuf[j + 4] * 64 + cw);
        uint4 B5 = *(const uint4*)(t_edge + (long long)ebuf[j + 5] * 64 + cw);
        uint4 B6 = *(const uint4*)(t_edge + (long long)ebuf[j + 6] * 64 + cw);
        uint4 B7 = *(const uint4*)(t_edge + (long long)ebuf[j + 7] * 64 + cw);
        bf8_acc(A0, a); bf8_acc(A1, a2); bf8_acc(A2, a); bf8_acc(A3, a2);
        bf8_acc(A4, a); bf8_acc(A5, a2); bf8_acc(A6, a); bf8_acc(A7, a2);
        A0 = B0; A1 = B1; A2 = B2; A3 = B3;
        A4 = B4; A5 = B5; A6 = B6; A7 = B7;
      }
      bf8_acc(A0, a); bf8_acc(A1, a2); bf8_acc(A2, a); bf8_acc(A3, a2);
      bf8_acc(A4, a); bf8_acc(A5, a2); bf8_acc(A6, a); bf8_acc(A7, a2);
    }
    for (; j < e0; ++j) {
      uint4 v = *(const uint4*)(t_edge + (long long)ebuf[j] * 64 + cw);
      bf8_acc(v, a);
    }
#pragma unroll
    for (int t = 0; t < 8; ++t) a[t] += a2[t];
    float inv = 1.0f / fmaxf((float)deg, 1.0f);
    float4 o0, o1;
    o0.x = fmaf(a[0], inv, b0.x); o0.y = fmaf(a[1], inv, b0.y);
    o0.z = fmaf(a[2], inv, b0.z); o0.w = fmaf(a[3], inv, b0.w);
    o1.x = fmaf(a[4], inv, b1.x); o1.y = fmaf(a[5], inv, b1.y);
    o1.z = fmaf(a[6], inv, b1.z); o1.w = fmaf(a[7], inv, b1.w);
    float* op = out + (long long)gn * kD + lane * 8;
    *(float4*)op = o0;
    *(float4*)(op + 4) = o1;
  }
}

extern "C" void kernel_launch(void* const* d_in, const int* in_sizes, int n_in,
                              void* d_out, int out_size, void* d_ws, size_t ws_size,
                              hipStream_t stream) {
  const float* feat      = (const float*)d_in[0];
  const float* W         = (const float*)d_in[1];
  const float* b         = (const float*)d_in[2];
  const int*   node_idx  = (const int*)d_in[3];
  const int*   hedge_idx = (const int*)d_in[4];

  const int n_pairs  = in_sizes[3];
  const int n_nodes  = in_sizes[0] / kD;
  const int n_hedges = kHedges;
  const int n_feat   = in_sizes[0];

  // feat_bf lives in d_out's buffer (25.6 of 51.2 MB; dead until final kernel)
  unsigned* feat_bf = (unsigned*)d_out;

  // Workspace (~19.9 MB)
  const int n_rows_pad = ((n_hedges + 63) / 64) * 64;          // 20032
  unsigned* t_edge = (unsigned*)d_ws;                          // 20032*64 words
  int* buf_e = (int*)(t_edge + (size_t)n_rows_pad * 64);       // kNCE*kCapCE
  int* buf_n = buf_e + (size_t)kNCE * kCapCE;                  // kNCN*kCapCN
  int* seg_e = buf_n + (size_t)kNCN * kCapCN;                  // kNCE*129
  int* seg_n = seg_e + (size_t)kNCE * 129;                     // kNCN*257
  int* gcnt_e = seg_n + (size_t)kNCN * 257;                    // kNCE
  int* gcnt_n = gcnt_e + kNCE;                                 // kNCN
  unsigned* Wbf = (unsigned*)(gcnt_n + kNCN);                  // kD*64 words (32 KB)

  hipMemsetAsync(gcnt_e, 0, (size_t)(kNCE + kNCN) * sizeof(int), stream);

  // chunk grid sized so per_block = ceil(n_pairs/pgrid) <= kPmax (LDS staging cap)
  int pgrid = (n_pairs + kPmax - 1) / kPmax;
  if (pgrid < 512) pgrid = 512;

  partition_coarse<<<2 * pgrid, 512, 0, stream>>>(
      feat, feat_bf, n_feat, W, Wbf,
      node_idx, hedge_idx, n_pairs, pgrid, gcnt_e, buf_e, gcnt_n, buf_n);

  subsort_edge<<<kNCE, 1024, 0, stream>>>(buf_e, gcnt_e, seg_e);

  gather_edge_sortn<<<kNCN + (n_hedges + 15) / 16, 256, 0, stream>>>(
      feat_bf, buf_e, seg_e, Wbf, t_edge, n_hedges,
      buf_n, gcnt_n, seg_n);

  gather_node_v4<<<(n_nodes + 63) / 64, 256, 0, stream>>>(
      t_edge, buf_n, seg_n, b, (float*)d_out, n_nodes);
}

// Round 12
// 247.846 us; speedup vs baseline: 1.0203x; 1.0203x over previous
//
#include <hip/hip_runtime.h>

static constexpr int kD = 128;
static constexpr int kHedges = 20000;

// Coarse partition: edge by h>>7 (128 hedges/bucket), node by n>>9 (512 nodes/bucket)
static constexpr int kNCE = 157;      // ceil(20000/128)
static constexpr int kCapCE = 11264;  // mean 10240 + 10 sigma
static constexpr int kNCN = 196;      // ceil(100000/512)
static constexpr int kCapCN = 9216;   // mean 8192 + 11 sigma
// gather slice caps
static constexpr int kSliceE4 = 1664; // 16 hedges/block: mean 1280 + ~10.6 sigma
static constexpr int kSliceN4 = 1408; // 64 nodes/block: mean 1024 + ~12 sigma
// partition block-local staging capacity (per_block = ceil(n_pairs/pgrid) must be <= this)
static constexpr int kPmax = 3200;    // 512 chunks: long runs -> coalesced writeback wins
static constexpr int kNBmax = 196;    // max(kNCE, kNCN)

typedef __attribute__((ext_vector_type(8))) short bf16x8;
typedef __attribute__((ext_vector_type(4))) float f32x4;

__device__ __forceinline__ float u2f(unsigned u) { return __uint_as_float(u); }
__device__ __forceinline__ unsigned f2u(float f) { return __float_as_uint(f); }

// round-to-nearest-even fp32 -> bf16, pack two into one uint
__device__ __forceinline__ unsigned bfpack(float x, float y) {
  unsigned ux = f2u(x); ux = (ux + 0x7FFFu + ((ux >> 16) & 1u)) >> 16;
  unsigned uy = f2u(y); uy = (uy + 0x7FFFu + ((uy >> 16) & 1u)) & 0xFFFF0000u;
  return ux | uy;
}
// accumulate 8 bf16 (uint4) into a[0..7]
__device__ __forceinline__ void bf8_acc(uint4 v, float* a) {
  a[0] += u2f(v.x << 16); a[1] += u2f(v.x & 0xFFFF0000u);
  a[2] += u2f(v.y << 16); a[3] += u2f(v.y & 0xFFFF0000u);
  a[4] += u2f(v.z << 16); a[5] += u2f(v.z & 0xFFFF0000u);
  a[6] += u2f(v.w << 16); a[7] += u2f(v.w & 0xFFFF0000u);
}

// ---------- L1: convert feats + W (fused) + partition pairs into coarse buckets ----
// Split by key side: blocks [0,pgrid) edge keying, [pgrid,2*pgrid) node keying.
// v2: pass-1 stashes the packed pair in LDS (lraw) while histogramming, so pass-2's
// placement chain is pure-LDS (load->atomic->store, ~40cy) instead of re-reading
// both index arrays from global (~250cy chain). 3 global sweeps -> 2 per side.
__global__ __launch_bounds__(512) void partition_coarse(
    const float* __restrict__ feat, unsigned* __restrict__ feat_bf, int n_feat,
    const float* __restrict__ W, unsigned* __restrict__ Wbf,
    const int* __restrict__ node_idx, const int* __restrict__ hedge_idx,
    int n_pairs, int pgrid,
    int* __restrict__ gcnt_e, int* __restrict__ buf_e,
    int* __restrict__ gcnt_n, int* __restrict__ buf_n) {
  __shared__ unsigned lraw[kPmax];            // 12.8 KB: packed pairs, chunk order
  __shared__ unsigned lbuf[kPmax];            // 12.8 KB: bucket-sorted pairs
  __shared__ int hist[kNBmax], gshift[kNBmax];
  __shared__ int wtot[8];
  const int tid = threadIdx.x;
  // fused feature conversion (grid-stride over uint4 groups of 8 floats)
  {
    const int n8 = n_feat >> 3;
    for (int t = blockIdx.x * 512 + tid; t < n8; t += gridDim.x * 512) {
      long long i = (long long)t * 8;
      const float4 v0 = *(const float4*)(feat + i);
      const float4 v1 = *(const float4*)(feat + i + 4);
      uint4 o;
      o.x = bfpack(v0.x, v0.y); o.y = bfpack(v0.z, v0.w);
      o.z = bfpack(v1.x, v1.y); o.w = bfpack(v1.z, v1.w);
      *(uint4*)(feat_bf + (i >> 1)) = o;
    }
  }
  // fused W bf16 packing, ROW-major for MFMA B-frags:
  // Wbf[row*64 + m] = {W[row][2m], W[row][2m+1]}  (32 KB total)
  for (int t = blockIdx.x * 512 + tid; t < kD * 64; t += gridDim.x * 512) {
    int row = t >> 6, m = t & 63;
    Wbf[t] = bfpack(W[row * kD + 2 * m], W[row * kD + 2 * m + 1]);
  }
  // side selection (uniform per block -> no divergence)
  const bool isEdge = (blockIdx.x < pgrid);
  const int cchunk = isEdge ? blockIdx.x : blockIdx.x - pgrid;
  const int per_block = (n_pairs + pgrid - 1) / pgrid;
  const int s = cchunk * per_block;
  const int e = min(s + per_block, n_pairs);
  const int cnt = max(e - s, 0);              // <= kPmax by grid sizing
  const int nb      = isEdge ? kNCE : kNCN;
  const int shift   = isEdge ? 7 : 9;         // key -> coarse bucket
  const int pshift  = isEdge ? 15 : 17;       // payload pack shift (h<2^15, n<2^17)
  const int* __restrict__ kidx = isEdge ? hedge_idx : node_idx;
  const int* __restrict__ pidx = isEdge ? node_idx : hedge_idx;
  int* __restrict__ gcnt = isEdge ? gcnt_e : gcnt_n;
  int* __restrict__ bufo = isEdge ? buf_e : buf_n;
  const long long capc = isEdge ? kCapCE : kCapCN;
  const unsigned kmask = (1u << pshift) - 1u;
  const int lowmask = (1 << shift) - 1;

  for (int i = tid; i < nb; i += 512) hist[i] = 0;
  __syncthreads();
  // pass 1: histogram + stash packed pair in LDS (single global sweep)
  for (int i = s + tid; i < e; i += 512) {
    const unsigned k = (unsigned)kidx[i];
    const unsigned p = (unsigned)pidx[i];
    lraw[i - s] = (p << pshift) | k;
    atomicAdd(&hist[k >> shift], 1);
  }
  __syncthreads();
  // exclusive scan of hist[0..nb) (nb <= 196 <= 512 threads, wave-hierarchical)
  {
    const int lane = tid & 63, wid = tid >> 6;
    int v = (tid < nb) ? hist[tid] : 0;
    int x = v;
#pragma unroll
    for (int d = 1; d < 64; d <<= 1) {
      int y = __shfl_up(x, d, 64);
      if (lane >= d) x += y;
    }
    if (lane == 63) wtot[wid] = x;
    __syncthreads();
    int add = 0;
    for (int w = 0; w < wid; ++w) add += wtot[w];
    if (tid < nb) {
      int lofs = x + add - v;
      int base = (v > 0) ? atomicAdd(&gcnt[tid], v) : 0;
      gshift[tid] = base - lofs;   // global pos = gshift[b] + lds_slot
      hist[tid] = lofs;            // reuse as placement cursor
    }
  }
  __syncthreads();
  // pass 2: pure-LDS counting-sort placement (no global reads)
  for (int i = tid; i < cnt; i += 512) {
    const unsigned v = lraw[i];
    const int b = (int)((v & kmask) >> shift);
    const int pos = atomicAdd(&hist[b], 1);
    lbuf[pos] = v;
  }
  __syncthreads();
  // writeback: consecutive LDS slots within a bucket run -> consecutive global
  // addresses (coalesced, full lines, one XCD per run)
  for (int i = tid; i < cnt; i += 512) {
    const unsigned v = lbuf[i];
    const int k = (int)(v & kmask);
    const int p = (int)(v >> pshift);
    const int b = k >> shift;
    const int pe = gshift[b] + i;
    if (pe < capc) bufo[(long long)b * capc + pe] = (p << shift) | (k & lowmask);
  }
}

// ---------- L2: sort each coarse bucket by low key bits, in place; emit segs ----------
// blocks [0,kNCE): edge buckets (128 bins); [kNCE, kNCE+kNCN): node buckets (512 bins).
__global__ __launch_bounds__(1024) void subsort_kernel(
    int* __restrict__ buf_e, const int* __restrict__ gcnt_e, int* __restrict__ seg_e,
    int* __restrict__ buf_n, const int* __restrict__ gcnt_n, int* __restrict__ seg_n) {
  __shared__ int sbuf[kCapCE];       // 45 KB
  __shared__ int bins[513];
  __shared__ int cur[512];
  __shared__ int segs[513];
  __shared__ int wtot[16];
  const int tid = threadIdx.x;
  int nbins, shift, cnt; int* src; int* segout;
  if (blockIdx.x < kNCE) {
    int cb = blockIdx.x; nbins = 128; shift = 7;
    src = buf_e + (long long)cb * kCapCE;
    cnt = min(gcnt_e[cb], kCapCE);
    segout = seg_e + cb * 129;
  } else {
    int cb = blockIdx.x - kNCE; nbins = 512; shift = 9;
    src = buf_n + (long long)cb * kCapCN;
    cnt = min(gcnt_n[cb], kCapCN);
    segout = seg_n + cb * 513;
  }
  const int mask = nbins - 1;
  for (int i = tid; i < nbins; i += 1024) bins[i] = 0;
  __syncthreads();
  for (int i = tid; i < cnt; i += 1024) atomicAdd(&bins[src[i] & mask], 1);
  __syncthreads();
  // hierarchical exclusive scan of bins[0..nbins) (16 waves of 64)
  const int lane = tid & 63, wid = tid >> 6;
  int v = (tid < nbins) ? bins[tid] : 0;
  int x = v;
#pragma unroll
  for (int d = 1; d < 64; d <<= 1) {
    int y = __shfl_up(x, d, 64);
    if (lane >= d) x += y;
  }
  if (lane == 63) wtot[wid] = x;
  __syncthreads();
  int add = 0;
  for (int w = 0; w < wid; ++w) add += wtot[w];
  if (tid < nbins) { segs[tid + 1] = x + add; cur[tid] = x + add - v; }
  if (tid == 0) segs[0] = 0;
  __syncthreads();
  for (int i = tid; i < cnt; i += 1024) {
    int p = src[i];
    int r = atomicAdd(&cur[p & mask], 1);
    sbuf[r] = p >> shift;              // payload only: sorted adjacency
  }
  __syncthreads();
  for (int i = tid; i < cnt; i += 1024) src[i] = sbuf[i];   // coalesced writeback
  for (int j = tid; j <= nbins; j += 1024) segout[j] = segs[j];
}

// ---------- gather features -> mean -> @ W.T via MFMA, write t_edge bf16 ----------
// 256 thr / 16 hedges per block. GEMM: D[16x128] = hbf(16x128 bf16) x W^T via
// 32x mfma_f32_16x16x32_bf16 (4 waves x 2 col-tiles x 4 k-steps). B-frags read
// from row-major bf16 Wbf (32 KB, L1-resident). Gather phase is at its
// random-fetch fabric roofline (172 MB compulsory @ ~3.1 TB/s); GEMM rides free.
__global__ __launch_bounds__(256) void gather_edge_fused(
    const unsigned* __restrict__ feat_bf, const int* __restrict__ buf_e,
    const int* __restrict__ seg_e, const unsigned* __restrict__ Wbf,
    unsigned* __restrict__ t_edge, int n_hedges) {
  __shared__ int ebuf[kSliceE4];           // 6.6 KB
  __shared__ int segl[17];
  __shared__ unsigned hbf[16][68];         // 4.3 KB bf16-packed mean rows (pad 68)
  __shared__ float hout[16][132];          // 8.4 KB GEMM result (pad 132)
  const int b = blockIdx.x;                // 16 hedges per block
  const int tid = threadIdx.x;
  const int h0 = b * 16;
  const int cb = h0 >> 7, j0 = h0 & 127;
  if (tid < 17) segl[tid] = seg_e[cb * 129 + j0 + tid];
  __syncthreads();
  const int sbase = segl[0];
  const int n_sl = min(segl[16] - sbase, kSliceE4);
  const int* src = buf_e + (long long)cb * kCapCE + sbase;
  for (int i = tid; i < n_sl; i += 256) ebuf[i] = src[i];
  __syncthreads();
  const int g = tid >> 4, lane = tid & 15, cw = lane * 4;
  const int gh = h0 + g;
  float a[8] = {}, a2[8] = {};
  int deg = 0;
  if (gh < n_hedges) {
    deg = segl[g + 1] - segl[g];
    const int s0 = min(segl[g] - sbase, n_sl);
    const int e0 = min(segl[g + 1] - sbase, n_sl);
    int j = s0;
    const int jend8 = s0 + ((e0 - s0) & ~7);
    if (j < jend8) {
      uint4 A0 = *(const uint4*)(feat_bf + (long long)ebuf[j] * 64 + cw);
      uint4 A1 = *(const uint4*)(feat_bf + (long long)ebuf[j + 1] * 64 + cw);
      uint4 A2 = *(const uint4*)(feat_bf + (long long)ebuf[j + 2] * 64 + cw);
      uint4 A3 = *(const uint4*)(feat_bf + (long long)ebuf[j + 3] * 64 + cw);
      uint4 A4 = *(const uint4*)(feat_bf + (long long)ebuf[j + 4] * 64 + cw);
      uint4 A5 = *(const uint4*)(feat_bf + (long long)ebuf[j + 5] * 64 + cw);
      uint4 A6 = *(const uint4*)(feat_bf + (long long)ebuf[j + 6] * 64 + cw);
      uint4 A7 = *(const uint4*)(feat_bf + (long long)ebuf[j + 7] * 64 + cw);
      j += 8;
      for (; j < jend8; j += 8) {
        uint4 B0 = *(const uint4*)(feat_bf + (long long)ebuf[j] * 64 + cw);
        uint4 B1 = *(const uint4*)(feat_bf + (long long)ebuf[j + 1] * 64 + cw);
        uint4 B2 = *(const uint4*)(feat_bf + (long long)ebuf[j + 2] * 64 + cw);
        uint4 B3 = *(const uint4*)(feat_bf + (long long)ebuf[j + 3] * 64 + cw);
        uint4 B4 = *(const uint4*)(feat_bf + (long long)ebuf[j + 4] * 64 + cw);
        uint4 B5 = *(const uint4*)(feat_bf + (long long)ebuf[j + 5] * 64 + cw);
        uint4 B6 = *(const uint4*)(feat_bf + (long long)ebuf[j + 6] * 64 + cw);
        uint4 B7 = *(const uint4*)(feat_bf + (long long)ebuf[j + 7] * 64 + cw);
        bf8_acc(A0, a); bf8_acc(A1, a2); bf8_acc(A2, a); bf8_acc(A3, a2);
        bf8_acc(A4, a); bf8_acc(A5, a2); bf8_acc(A6, a); bf8_acc(A7, a2);
        A0 = B0; A1 = B1; A2 = B2; A3 = B3;
        A4 = B4; A5 = B5; A6 = B6; A7 = B7;
      }
      bf8_acc(A0, a); bf8_acc(A1, a2); bf8_acc(A2, a); bf8_acc(A3, a2);
      bf8_acc(A4, a); bf8_acc(A5, a2); bf8_acc(A6, a); bf8_acc(A7, a2);
    }
    for (; j < e0; ++j) {
      uint4 v = *(const uint4*)(feat_bf + (long long)ebuf[j] * 64 + cw);
      bf8_acc(v, a);
    }
  }
  {
    const float inv = 1.0f / fmaxf((float)deg, 1.0f);
    uint4 o;
    o.x = bfpack((a[0] + a2[0]) * inv, (a[1] + a2[1]) * inv);
    o.y = bfpack((a[2] + a2[2]) * inv, (a[3] + a2[3]) * inv);
    o.z = bfpack((a[4] + a2[4]) * inv, (a[5] + a2[5]) * inv);
    o.w = bfpack((a[6] + a2[6]) * inv, (a[7] + a2[7]) * inv);
    *(uint4*)(&hbf[g][cw]) = o;   // row stride 68 words = 272 B (16B-aligned)
  }
  __syncthreads();
  // MFMA GEMM: wave wv handles col-tiles 2wv, 2wv+1.
  // A frag: lane l holds A[row=l&15][k=(l>>4)*8+j]; B frag: B[k][col=l&15], same k.
  // B[k][c] = W[c][k] -> 8 consecutive k of row c of Wbf = one uint4.
  {
    const int wv = tid >> 6;
    const int l = tid & 63;
    const int frow = l & 15;
    const int kgrp = l >> 4;
    f32x4 acc0 = {0.f, 0.f, 0.f, 0.f}, acc1 = {0.f, 0.f, 0.f, 0.f};
#pragma unroll
    for (int kk = 0; kk < 4; ++kk) {
      const int wofs = kk * 16 + kgrp * 4;
      bf16x8 af = *(const bf16x8*)(&hbf[frow][wofs]);
      bf16x8 bf0 = *(const bf16x8*)(Wbf + ((2 * wv) * 16 + frow) * 64 + wofs);
      bf16x8 bf1 = *(const bf16x8*)(Wbf + ((2 * wv + 1) * 16 + frow) * 64 + wofs);
      acc0 = __builtin_amdgcn_mfma_f32_16x16x32_bf16(af, bf0, acc0, 0, 0, 0);
      acc1 = __builtin_amdgcn_mfma_f32_16x16x32_bf16(af, bf1, acc1, 0, 0, 0);
    }
    // C/D layout: col = l&15, row = (l>>4)*4 + r  [m89-verified]
#pragma unroll
    for (int r = 0; r < 4; ++r) {
      hout[kgrp * 4 + r][(2 * wv) * 16 + frow] = acc0[r];
      hout[kgrp * 4 + r][(2 * wv + 1) * 16 + frow] = acc1[r];
    }
  }
  __syncthreads();
  if (gh < n_hedges) {
    const float* hr = &hout[g][lane * 8];
    uint4 o;
    o.x = bfpack(hr[0], hr[1]);
    o.y = bfpack(hr[2], hr[3]);
    o.z = bfpack(hr[4], hr[5]);
    o.w = bfpack(hr[6], hr[7]);
    *(uint4*)(t_edge + (long long)gh * 64 + cw) = o;
  }
}

// ---------- gather t_edge -> fp32 out (mean) + bias, MLP-pipelined ----------
// 256 thr / 64 nodes per block (16 groups x 16 lanes, 4 nodes per group).
__global__ __launch_bounds__(256) void gather_node_v4(
    const unsigned* __restrict__ t_edge, const int* __restrict__ buf_n,
    const int* __restrict__ seg_n, const float* __restrict__ bias,
    float* __restrict__ out, int n_nodes) {
  __shared__ int ebuf[kSliceN4];
  __shared__ int segl[65];
  const int b = blockIdx.x;            // 64 nodes per block
  const int tid = threadIdx.x;
  const int n0 = b * 64;
  const int cb = n0 >> 9, j0 = n0 & 511;
  if (tid < 65) segl[tid] = seg_n[cb * 513 + j0 + tid];
  __syncthreads();
  const int sbase = segl[0];
  const int n_sl = min(segl[64] - sbase, kSliceN4);
  const int* src = buf_n + (long long)cb * kCapCN + sbase;
  for (int i = tid; i < n_sl; i += 256) ebuf[i] = src[i];
  __syncthreads();
  const int g = tid >> 4, lane = tid & 15, cw = lane * 4;
  const float4 b0 = *(const float4*)(bias + lane * 8);
  const float4 b1 = *(const float4*)(bias + lane * 8 + 4);
  for (int nl = g; nl < 64; nl += 16) {
    int gn = n0 + nl;
    if (gn >= n_nodes) continue;
    const int deg = segl[nl + 1] - segl[nl];
    const int s0 = min(segl[nl] - sbase, n_sl);
    const int e0 = min(segl[nl + 1] - sbase, n_sl);
    float a[8] = {}, a2[8] = {};
    int j = s0;
    const int jend8 = s0 + ((e0 - s0) & ~7);
    if (j < jend8) {
      uint4 A0 = *(const uint4*)(t_edge + (long long)ebuf[j] * 64 + cw);
      uint4 A1 = *(const uint4*)(t_edge + (long long)ebuf[j + 1] * 64 + cw);
      uint4 A2 = *(const uint4*)(t_edge + (long long)ebuf[j + 2] * 64 + cw);
      uint4 A3 = *(const uint4*)(t_edge + (long long)ebuf[j + 3] * 64 + cw);
      uint4 A4 = *(const uint4*)(t_edge + (long long)ebuf[j + 4] * 64 + cw);
      uint4 A5 = *(const uint4*)(t_edge + (long long)ebuf[j + 5] * 64 + cw);
      uint4 A6 = *(const uint4*)(t_edge + (long long)ebuf[j + 6] * 64 + cw);
      uint4 A7 = *(const uint4*)(t_edge + (long long)ebuf[j + 7] * 64 + cw);
      j += 8;
      for (; j < jend8; j += 8) {
        uint4 B0 = *(const uint4*)(t_edge + (long long)ebuf[j] * 64 + cw);
        uint4 B1 = *(const uint4*)(t_edge + (long long)ebuf[j + 1] * 64 + cw);
        uint4 B2 = *(const uint4*)(t_edge + (long long)ebuf[j + 2] * 64 + cw);
        uint4 B3 = *(const uint4*)(t_edge + (long long)ebuf[j + 3] * 64 + cw);
        uint4 B4 = *(const uint4*)(t_edge + (long long)ebuf[j + 4] * 64 + cw);
        uint4 B5 = *(const uint4*)(t_edge + (long long)ebuf[j + 5] * 64 + cw);
        uint4 B6 = *(const uint4*)(t_edge + (long long)ebuf[j + 6] * 64 + cw);
        uint4 B7 = *(const uint4*)(t_edge + (long long)ebuf[j + 7] * 64 + cw);
        bf8_acc(A0, a); bf8_acc(A1, a2); bf8_acc(A2, a); bf8_acc(A3, a2);
        bf8_acc(A4, a); bf8_acc(A5, a2); bf8_acc(A6, a); bf8_acc(A7, a2);
        A0 = B0; A1 = B1; A2 = B2; A3 = B3;
        A4 = B4; A5 = B5; A6 = B6; A7 = B7;
      }
      bf8_acc(A0, a); bf8_acc(A1, a2); bf8_acc(A2, a); bf8_acc(A3, a2);
      bf8_acc(A4, a); bf8_acc(A5, a2); bf8_acc(A6, a); bf8_acc(A7, a2);
    }
    for (; j < e0; ++j) {
      uint4 v = *(const uint4*)(t_edge + (long long)ebuf[j] * 64 + cw);
      bf8_acc(v, a);
    }
#pragma unroll
    for (int t = 0; t < 8; ++t) a[t] += a2[t];
    float inv = 1.0f / fmaxf((float)deg, 1.0f);
    float4 o0, o1;
    o0.x = fmaf(a[0], inv, b0.x); o0.y = fmaf(a[1], inv, b0.y);
    o0.z = fmaf(a[2], inv, b0.z); o0.w = fmaf(a[3], inv, b0.w);
    o1.x = fmaf(a[4], inv, b1.x); o1.y = fmaf(a[5], inv, b1.y);
    o1.z = fmaf(a[6], inv, b1.z); o1.w = fmaf(a[7], inv, b1.w);
    float* op = out + (long long)gn * kD + lane * 8;
    *(float4*)op = o0;
    *(float4*)(op + 4) = o1;
  }
}

extern "C" void kernel_launch(void* const* d_in, const int* in_sizes, int n_in,
                              void* d_out, int out_size, void* d_ws, size_t ws_size,
                              hipStream_t stream) {
  const float* feat      = (const float*)d_in[0];
  const float* W         = (const float*)d_in[1];
  const float* b         = (const float*)d_in[2];
  const int*   node_idx  = (const int*)d_in[3];
  const int*   hedge_idx = (const int*)d_in[4];

  const int n_pairs  = in_sizes[3];
  const int n_nodes  = in_sizes[0] / kD;
  const int n_hedges = kHedges;
  const int n_feat   = in_sizes[0];

  // feat_bf lives in d_out's buffer (25.6 of 51.2 MB; dead until final kernel)
  unsigned* feat_bf = (unsigned*)d_out;

  // Workspace (~20 MB)
  const int n_rows_pad = ((n_hedges + 63) / 64) * 64;          // 20032
  unsigned* t_edge = (unsigned*)d_ws;                          // 20032*64 words
  int* buf_e = (int*)(t_edge + (size_t)n_rows_pad * 64);       // kNCE*kCapCE
  int* buf_n = buf_e + (size_t)kNCE * kCapCE;                  // kNCN*kCapCN
  int* seg_e = buf_n + (size_t)kNCN * kCapCN;                  // kNCE*129
  int* seg_n = seg_e + (size_t)kNCE * 129;                     // kNCN*513
  int* gcnt_e = seg_n + (size_t)kNCN * 513;                    // kNCE
  int* gcnt_n = gcnt_e + kNCE;                                 // kNCN
  unsigned* Wbf = (unsigned*)(gcnt_n + kNCN);                  // kD*64 words (32 KB)

  hipMemsetAsync(gcnt_e, 0, (size_t)(kNCE + kNCN) * sizeof(int), stream);

  // chunk grid sized so per_block = ceil(n_pairs/pgrid) <= kPmax (LDS staging cap)
  int pgrid = (n_pairs + kPmax - 1) / kPmax;
  if (pgrid < 512) pgrid = 512;

  partition_coarse<<<2 * pgrid, 512, 0, stream>>>(
      feat, feat_bf, n_feat, W, Wbf,
      node_idx, hedge_idx, n_pairs, pgrid, gcnt_e, buf_e, gcnt_n, buf_n);

  subsort_kernel<<<kNCE + kNCN, 1024, 0, stream>>>(
      buf_e, gcnt_e, seg_e, buf_n, gcnt_n, seg_n);

  gather_edge_fused<<<(n_hedges + 15) / 16, 256, 0, stream>>>(
      feat_bf, buf_e, seg_e, Wbf, t_edge, n_hedges);

  gather_node_v4<<<(n_nodes + 63) / 64, 256, 0, stream>>>(
      t_edge, buf_n, seg_n, b, (float*)d_out, n_nodes);
}